// Round 22
// baseline (50.209 us; speedup 1.0000x reference)
//
#include <hip/hip_runtime.h>
#include <hip/hip_fp16.h>

#define BATCH   16384
#define NKNOW   128
#define NEDGE   253
#define RPB     16

typedef __attribute__((ext_vector_type(8))) short  s16x8;   // 8 bf16 MFMA operand
typedef __attribute__((ext_vector_type(4))) float  f32x4;   // MFMA accumulator
typedef __attribute__((ext_vector_type(4))) int    i32x4;

typedef unsigned short u16;
typedef unsigned int   u32;
typedef unsigned long long u64;

__device__ __forceinline__ float sigm(float x) { return 1.0f / (1.0f + __expf(-x)); }

__device__ __forceinline__ u16 f2bf_rn(float x) {
    u32 u = __float_as_uint(x);
    u += 0x7FFFu + ((u >> 16) & 1u);
    return (u16)(u >> 16);
}
__device__ __forceinline__ float bf2f(u16 h) { return __uint_as_float(((u32)h) << 16); }

// centered-f16 pack: store f16(c - 0.5) for c in (0,1); half-ulp <= ~1.2e-4
__device__ __forceinline__ u16 f2hc(float x) {
    __half h = __float2half_rn(x - 0.5f);
    u16 v; __builtin_memcpy(&v, &h, 2); return v;
}
__device__ __forceinline__ float h2fc(u32 u) {      // low 16 bits -> centered value
    u16 v = (u16)u; __half h; __builtin_memcpy(&h, &v, 2);
    return __half2float(h);
}

// R1-proven LDS swizzle: row-major 256B rows, XOR bits 4-6 with row&7
__device__ __forceinline__ int swz(int row, int kbyte) {
    return row * 256 + (kbyte ^ ((row & 7) << 4));
}
__device__ __forceinline__ void store_pair(char* Mh, char* Ml, int r, int k0, float va, float vb) {
    int off = swz(r, k0 * 2);
    u16 ha = f2bf_rn(va); u16 la = f2bf_rn(va - bf2f(ha));
    u16 hb = f2bf_rn(vb); u16 lb = f2bf_rn(vb - bf2f(hb));
    *(u32*)(Mh + off) = (u32)ha | ((u32)hb << 16);
    *(u32*)(Ml + off) = (u32)la | ((u32)lb << 16);
}

// ======================= K1: gather (+ D-prep + merged conv_w) =============
// cbT16[slot][row]: slot-major centered-f16 chain coeffs (R19-proven).
// NEW: D = sigm(diff)*know computed here (wave-per-row MLP) and stored as
// packed u32 pairs dhiw/dlow/kmw[row*64 + j] (elements 2j, 2j+1).
__global__ __launch_bounds__(256, 4) void gather_ncd(
    const int*   __restrict__ user_ids,
    const int*   __restrict__ item_ids,
    const float* __restrict__ item_know,
    const float* __restrict__ priori,
    const float* __restrict__ condi_p,
    const float* __restrict__ condi_n,
    const float* __restrict__ item_diff_w,
    const float* __restrict__ Wu,
    const float* __restrict__ Wi,
    u16*         __restrict__ wsp,
    uint2*       __restrict__ cbT16,
    u32*         __restrict__ dhiw,
    u32*         __restrict__ dlow,
    u32*         __restrict__ kmw)
{
    __shared__ float4 stage[4][128];        // [rr][slot], 8 KB

    const int wid = threadIdx.x >> 6, j = threadIdx.x & 63;
    const int r0  = blockIdx.x * 4;
    const int row = r0 + wid;
    const int uid = user_ids[row];
    const int iid = item_ids[row];
    const float* cp = condi_p + (size_t)uid * NEDGE;
    const float* cn = condi_n + (size_t)uid * NEDGE;
    const float* kw = item_know   + (size_t)row * NKNOW;
    const float* dw = item_diff_w + (size_t)iid * NKNOW;

    // issue all independent loads up front
    float a0p = cp[127 + j], a0n = cn[127 + j], b0p = cp[1 + j], b0n = cn[1 + j];
    float a1p = 0.f, a1n = 0.f, b1p = 0.f, b1n = 0.f;
    if (j < 62) { a1p = cp[191 + j]; a1n = cn[191 + j]; b1p = cp[65 + j]; b1n = cn[65 + j]; }
    float2 k2 = *(const float2*)&kw[2 * j];
    float2 d2 = *(const float2*)&dw[2 * j];
    float c0p = cp[0], c0n = cn[0], pri = priori[(size_t)uid * NKNOW];

    float4 sA;
    sA.x = sqrtf(sigm(a0p)); sA.y = sqrtf(sigm(a0n));
    sA.z = sqrtf(sigm(b0p)); sA.w = sqrtf(sigm(b0n));
    stage[wid][1 + j] = sA;
    if (j < 62) {
        float4 sB;
        sB.x = sqrtf(sigm(a1p)); sB.y = sqrtf(sigm(a1n));
        sB.z = sqrtf(sigm(b1p)); sB.w = sqrtf(sigm(b1n));
        stage[wid][65 + j] = sB;
    }
    if (j == 0) {
        float4 h; h.x = sigm(c0p); h.y = sigm(c0n); h.z = sigm(pri); h.w = 0.5f;
        stage[wid][0] = h;
    }

    // D-prep (elements 2j, 2j+1), packed u32 stores (know in {0,1} -> exact)
    {
        float dv0 = sigm(d2.x) * k2.x, dv1 = sigm(d2.y) * k2.y;
        u16 h0 = f2bf_rn(dv0), h1 = f2bf_rn(dv1);
        u16 l0 = f2bf_rn(dv0 - bf2f(h0)), l1 = f2bf_rn(dv1 - bf2f(h1));
        const size_t o = (size_t)row * 64 + j;
        dhiw[o] = (u32)h0 | ((u32)h1 << 16);
        dlow[o] = (u32)l0 | ((u32)l1 << 16);
        kmw[o]  = ((k2.x > 0.5f) ? 0x0000FFFFu : 0u) | ((k2.y > 0.5f) ? 0xFFFF0000u : 0u);
    }
    __syncthreads();

    // transposed write-out (centered-f16 packed): 127 slots x 4 rows
    for (int idx = threadIdx.x; idx < 4 * 127; idx += 256) {
        const int slot = idx >> 2, rr = idx & 3;
        float4 v = stage[rr][slot];
        uint2 o;
        o.x = (u32)f2hc(v.x) | ((u32)f2hc(v.y) << 16);
        o.y = (u32)f2hc(v.z) | ((u32)f2hc(v.w) << 16);
        cbT16[(size_t)slot * BATCH + r0 + rr] = o;
    }

    // merged conv_w: blocks 0..255 convert Wu/Wi fp32 -> bf16 hi/lo in wsp
    if (blockIdx.x < 256) {
        int i = blockIdx.x * 256 + threadIdx.x;          // 0..65535
        bool isU = i < 32768;
        int  jj  = isU ? i : i - 32768;
        float w  = isU ? Wu[jj] : Wi[jj];
        u16 h = f2bf_rn(w);
        u16 l = f2bf_rn(w - bf2f(h));
        int base = isU ? 0 : 65536;
        wsp[base + jj]         = h;
        wsp[base + 32768 + jj] = l;
    }
}

// ======================= K2: chain + D-copy + gemm =========================
// 512 blocks x 256 thr, 32 rows/block; occ 2 (structurally proven).
// Phase A: wave0 lanes0-31 = 32 serial chains (coalesced cbT16 reads);
//          wave0 lanes32-63 = disc; waves1-2 = STREAMING copy of precomputed
//          dhiw/dlow/kmw -> swizzled LDS (no dependent chains, full MLP).
// Phase B: champion MFMA gemm (mask-AND on A), 2 row-groups of 16.
__global__ __launch_bounds__(256, 2) void cg_ncd(
    const int*   __restrict__ item_ids,
    const float* __restrict__ item_disc_w,
    const float* __restrict__ bu,
    const float* __restrict__ bi,
    const u16*   __restrict__ wsp,
    const uint2* __restrict__ cbT16,
    const u32*   __restrict__ dhiw,
    const u32*   __restrict__ dlow,
    const u32*   __restrict__ kmw,
    float*       __restrict__ out)
{
    __shared__ __align__(16) u16 sMh[32 * 128];
    __shared__ __align__(16) u16 sMl[32 * 128];
    __shared__ __align__(16) u16 sDh[32 * 128];
    __shared__ __align__(16) u16 sDl[32 * 128];
    __shared__ __align__(16) u16 sKm[32 * 128];
    __shared__ float sRed[4][32];
    __shared__ float sDisc[32];

    const int tid  = threadIdx.x;
    const int lane = tid & 63;
    const int wid  = tid >> 6;
    const int l15  = lane & 15, lq = lane >> 4;
    const int r0   = blockIdx.x * 32;

    if (wid == 0) {
        if (lane < 32) {
            // ---- 32 serial chains, coalesced cbT16 reads (R19-proven) ----
            const int r = lane;
            const uint2* base = cbT16 + (r0 + r);
            uint2 hh = base[0];
            float c0p = h2fc(hh.x) + 0.5f;
            float c0n = h2fc(hh.x >> 16) + 0.5f;
            float p0  = h2fc(hh.y) + 0.5f;
            float p1  = fmaf(p0, c0p - c0n, c0n);
            store_pair((char*)sMh, (char*)sMl, r, 0, p0, p1);

            float pm2 = p0, pm1 = p1, pev = 0.f;
            uint2 A[14], Bv[14];
#define LOADB(buf, bi_)                                               \
    _Pragma("unroll")                                                 \
    for (int t = 0; t < 14; ++t)                                      \
        buf[t] = base[(size_t)(1 + 14 * (bi_) + t) * BATCH];
#define STEPS(buf, bi_)                                               \
    _Pragma("unroll")                                                 \
    for (int t = 0; t < 14; ++t) {                                    \
        const int k = 2 + 14 * (bi_) + t;                             \
        uint2 sv = buf[t];                                            \
        float ax = h2fc(sv.x), ay = h2fc(sv.x >> 16);                 \
        float bx = h2fc(sv.y), by = h2fc(sv.y >> 16);                 \
        float ta = fmaf(pm2, ax - ay, ay + 0.5f);                     \
        float tb = fmaf(pm1, bx - by, by + 0.5f);                     \
        float pk = ta * tb;                                           \
        if (k & 1) store_pair((char*)sMh, (char*)sMl, r, k - 1, pev, pk); \
        else       pev = pk;                                          \
        pm2 = pm1; pm1 = pk;                                          \
    }
            LOADB(A, 0);
            LOADB(Bv, 1); STEPS(A, 0);
            LOADB(A, 2);  STEPS(Bv, 1);
            LOADB(Bv, 3); STEPS(A, 2);
            LOADB(A, 4);  STEPS(Bv, 3);
            LOADB(Bv, 5); STEPS(A, 4);
            LOADB(A, 6);  STEPS(Bv, 5);
            LOADB(Bv, 7); STEPS(A, 6);
            LOADB(A, 8);  STEPS(Bv, 7);
            STEPS(A, 8);
#undef LOADB
#undef STEPS
        } else {
            sDisc[lane - 32] = sigm(item_disc_w[item_ids[r0 + lane - 32]]);
        }
    } else if (wid <= 2) {
        // ---- waves 1-2: streaming copy ws -> swizzled LDS (no dep chains)
        const int rbase = (wid - 1) * 16;
        #pragma unroll 4
        for (int rr = 0; rr < 16; ++rr) {
            const int r = rbase + rr;
            const size_t o = (size_t)(r0 + r) * 64 + lane;
            u32 dh2 = dhiw[o];
            u32 dl2 = dlow[o];
            u32 km2 = kmw[o];
            const int off = swz(r, 4 * lane);             // elements 2j,2j+1
            *(u32*)((char*)sDh + off) = dh2;
            *(u32*)((char*)sDl + off) = dl2;
            *(u32*)((char*)sKm + off) = km2;
        }
    }
    __syncthreads();

    // ---------------- Phase B: MFMA gemm (champion verbatim) --------------
    const u16* WuH = wsp;
    const u16* WuL = wsp + 32768;
    const u16* WiH = wsp + 65536;
    const u16* WiL = wsp + 98304;

    float rowsum[2][4] = {{0.f,0.f,0.f,0.f},{0.f,0.f,0.f,0.f}};

    #pragma unroll 1
    for (int t = 0; t < 4; ++t) {
        const int hcol = wid * 64 + t * 16 + l15;
        s16x8 uh[4], ul[4], ih[4], il[4];
        #pragma unroll
        for (int kc = 0; kc < 4; ++kc) {
            const int ke = kc * 32 + lq * 8;
            uh[kc] = *(const s16x8*)(WuH + hcol * NKNOW + ke);
            ul[kc] = *(const s16x8*)(WuL + hcol * NKNOW + ke);
            ih[kc] = *(const s16x8*)(WiH + hcol * NKNOW + ke);
            il[kc] = *(const s16x8*)(WiL + hcol * NKNOW + ke);
        }
        const float bub = bu[hcol], bib = bi[hcol];

        #pragma unroll
        for (int rg = 0; rg < 2; ++rg) {
            const int lr = rg * 16 + l15;                 // LDS row 0..31
            f32x4 accU = {0.f, 0.f, 0.f, 0.f};
            f32x4 accV = {0.f, 0.f, 0.f, 0.f};
            #pragma unroll
            for (int kc = 0; kc < 4; ++kc) {
                const int offA = swz(lr, kc * 64 + lq * 16);
                i32x4 km = *(const i32x4*)((const char*)sKm + offA);
                i32x4 mh = *(const i32x4*)((const char*)sMh + offA) & km;
                i32x4 ml = *(const i32x4*)((const char*)sMl + offA) & km;
                s16x8 ah = *(s16x8*)&mh;
                s16x8 al = *(s16x8*)&ml;
                s16x8 dh = *(const s16x8*)((const char*)sDh + offA);
                s16x8 dl = *(const s16x8*)((const char*)sDl + offA);
                accU = __builtin_amdgcn_mfma_f32_16x16x32_bf16(ah, uh[kc], accU, 0, 0, 0);
                accU = __builtin_amdgcn_mfma_f32_16x16x32_bf16(ah, ul[kc], accU, 0, 0, 0);
                accU = __builtin_amdgcn_mfma_f32_16x16x32_bf16(al, uh[kc], accU, 0, 0, 0);
                accV = __builtin_amdgcn_mfma_f32_16x16x32_bf16(dh, ih[kc], accV, 0, 0, 0);
                accV = __builtin_amdgcn_mfma_f32_16x16x32_bf16(dh, il[kc], accV, 0, 0, 0);
                accV = __builtin_amdgcn_mfma_f32_16x16x32_bf16(dl, ih[kc], accV, 0, 0, 0);
            }
            #pragma unroll
            for (int j = 0; j < 4; ++j) {                 // C/D: col=l15, row=lq*4+j
                float x = accU[j] + bub;
                float u = 1.0f - 2.0f / (1.0f + __expf(2.0f * x));   // tanh
                float v = sigm(accV[j] + bib);
                rowsum[rg][j] += u * v;
            }
        }
    }

    #pragma unroll
    for (int rg = 0; rg < 2; ++rg)
        #pragma unroll
        for (int j = 0; j < 4; ++j) {
            float v = rowsum[rg][j];
            v += __shfl_xor(v, 1);
            v += __shfl_xor(v, 2);
            v += __shfl_xor(v, 4);
            v += __shfl_xor(v, 8);
            if (l15 == 0) sRed[wid][rg * 16 + lq * 4 + j] = v;
        }
    __syncthreads();

    if (tid < 32) {
        float s = sRed[0][tid] + sRed[1][tid] + sRed[2][tid] + sRed[3][tid];
        out[r0 + tid] = sigm(s - sDisc[tid]);
    }
}

// ======================= Fallback: R1 fused kernel (proven) ================
__global__ void conv_w(const float* __restrict__ Wu, const float* __restrict__ Wi,
                       u16* __restrict__ wsp) {
    int i = blockIdx.x * 256 + threadIdx.x;
    bool isU = i < 32768;
    int  j   = isU ? i : i - 32768;
    float w  = isU ? Wu[j] : Wi[j];
    u16 h = f2bf_rn(w);
    u16 l = f2bf_rn(w - bf2f(h));
    int base = isU ? 0 : 65536;
    wsp[base + j]         = h;
    wsp[base + 32768 + j] = l;
}

__global__ __launch_bounds__(256, 3) void fused_ncd(
    const int*   __restrict__ user_ids,
    const int*   __restrict__ item_ids,
    const float* __restrict__ item_know,
    const float* __restrict__ priori,
    const float* __restrict__ condi_p,
    const float* __restrict__ condi_n,
    const float* __restrict__ item_diff_w,
    const float* __restrict__ item_disc_w,
    const float* __restrict__ bu,
    const float* __restrict__ bi,
    const u16* __restrict__ wsp,
    float*       __restrict__ out)
{
    __shared__ float sPair[RPB][508];
    __shared__ __align__(16) u16 sMhi[RPB * 128];
    __shared__ __align__(16) u16 sMlo[RPB * 128];
    __shared__ __align__(16) u16 sDhi[RPB * 128];
    __shared__ __align__(16) u16 sDlo[RPB * 128];
    __shared__ __align__(16) u16 sKmF[RPB * 128];
    __shared__ float sRed[4][RPB];
    __shared__ float sDisc[RPB];

    const int tid  = threadIdx.x;
    const int lane = tid & 63;
    const int wid  = tid >> 6;
    const int r0   = blockIdx.x * RPB;

    for (int rr = 0; rr < 4; ++rr) {
        const int r   = wid * 4 + rr;
        const int row = r0 + r;
        const int uid = user_ids[row];
        const int iid = item_ids[row];
        const float* cp = condi_p + (size_t)uid * NEDGE;
        const float* cn = condi_n + (size_t)uid * NEDGE;
        for (int e = lane; e < NEDGE; e += 64) {
            float p = sigm(cp[e]);
            float n = sigm(cn[e]);
            if (e >= 1) { p = sqrtf(p); n = sqrtf(n); }
            *(float2*)&sPair[r][2 * e] = make_float2(p, n);
        }
        const float* dw = item_diff_w + (size_t)iid * NKNOW;
        const float* kw = item_know   + (size_t)row * NKNOW;
        for (int e = lane; e < NKNOW; e += 64) {
            float kv = kw[e];
            float dv = sigm(dw[e]) * kv;
            u16 dh = f2bf_rn(dv);
            u16 dl = f2bf_rn(dv - bf2f(dh));
            int off = swz(r, 2 * e);
            *(u16*)((char*)sDhi + off) = dh;
            *(u16*)((char*)sDlo + off) = dl;
            *(u16*)((char*)sKmF + off) = (kv > 0.5f) ? (u16)0xFFFFu : (u16)0;
        }
    }
    __syncthreads();

    if (tid < RPB) {
        const int r   = tid;
        const int row = r0 + r;
        const int uid = user_ids[row];
        const int iid = item_ids[row];
        const float* P = &sPair[r][0];
        float p0 = sigm(priori[(size_t)uid * NKNOW]);
        float2 c0 = *(const float2*)&P[0];
        float p1 = c0.x * p0 + c0.y * (1.0f - p0);
        store_pair((char*)sMhi, (char*)sMlo, r, 0, p0, p1);
        float pm2 = p0, pm1 = p1, pev = 0.0f;
        for (int k = 2; k < NKNOW; ++k) {
            float2 a = *(const float2*)&P[2 * (125 + k)];
            float2 b = *(const float2*)&P[2 * (k - 1)];
            float ta = fmaf(pm2, a.x - a.y, a.y);
            float tb = fmaf(pm1, b.x - b.y, b.y);
            float pk = ta * tb;
            if (k & 1) store_pair((char*)sMhi, (char*)sMlo, r, k - 1, pev, pk);
            else       pev = pk;
            pm2 = pm1; pm1 = pk;
        }
        sDisc[r] = sigm(item_disc_w[iid]);
    }
    __syncthreads();

    const int l15 = lane & 15, lq = lane >> 4;
    const u16* WuH = wsp;
    const u16* WuL = wsp + 32768;
    const u16* WiH = wsp + 65536;
    const u16* WiL = wsp + 98304;

    float rowsum[4] = {0.f, 0.f, 0.f, 0.f};

    for (int t = 0; t < 4; ++t) {
        const int hcol = wid * 64 + t * 16 + l15;
        f32x4 accU = {0.f, 0.f, 0.f, 0.f};
        f32x4 accV = {0.f, 0.f, 0.f, 0.f};
        const u16* wuh = WuH + hcol * NKNOW;
        const u16* wul = WuL + hcol * NKNOW;
        const u16* wih = WiH + hcol * NKNOW;
        const u16* wil = WiL + hcol * NKNOW;
        #pragma unroll
        for (int kc = 0; kc < 4; ++kc) {
            const int offA = swz(l15, kc * 64 + lq * 16);
            const int ke   = kc * 32 + lq * 8;
            i32x4 km = *(const i32x4*)((const char*)sKmF + offA);
            i32x4 mh = *(const i32x4*)((const char*)sMhi + offA) & km;
            i32x4 ml = *(const i32x4*)((const char*)sMlo + offA) & km;
            s16x8 ah = *(s16x8*)&mh;
            s16x8 al = *(s16x8*)&ml;
            s16x8 bh = *(const s16x8*)((const char*)sDhi + offA);
            s16x8 bl = *(const s16x8*)((const char*)sDlo + offA);
            s16x8 uh = *(const s16x8*)(wuh + ke);
            s16x8 ul = *(const s16x8*)(wul + ke);
            s16x8 ih = *(const s16x8*)(wih + ke);
            s16x8 il = *(const s16x8*)(wil + ke);
            accU = __builtin_amdgcn_mfma_f32_16x16x32_bf16(ah, uh, accU, 0, 0, 0);
            accU = __builtin_amdgcn_mfma_f32_16x16x32_bf16(ah, ul, accU, 0, 0, 0);
            accU = __builtin_amdgcn_mfma_f32_16x16x32_bf16(al, uh, accU, 0, 0, 0);
            accV = __builtin_amdgcn_mfma_f32_16x16x32_bf16(bh, ih, accV, 0, 0, 0);
            accV = __builtin_amdgcn_mfma_f32_16x16x32_bf16(bh, il, accV, 0, 0, 0);
            accV = __builtin_amdgcn_mfma_f32_16x16x32_bf16(bl, ih, accV, 0, 0, 0);
        }
        const float bub = bu[hcol], bib = bi[hcol];
        #pragma unroll
        for (int j = 0; j < 4; ++j) {
            float x = accU[j] + bub;
            float u = 1.0f - 2.0f / (1.0f + __expf(2.0f * x));
            float v = sigm(accV[j] + bib);
            rowsum[j] += u * v;
        }
    }

    #pragma unroll
    for (int j = 0; j < 4; ++j) {
        float v = rowsum[j];
        v += __shfl_xor(v, 1);
        v += __shfl_xor(v, 2);
        v += __shfl_xor(v, 4);
        v += __shfl_xor(v, 8);
        if (l15 == 0) sRed[wid][lq * 4 + j] = v;
    }
    __syncthreads();

    if (tid < RPB) {
        float logit = sRed[0][tid] + sRed[1][tid] + sRed[2][tid] + sRed[3][tid] - sDisc[tid];
        out[r0 + tid] = sigm(logit);
    }
}

extern "C" void kernel_launch(void* const* d_in, const int* in_sizes, int n_in,
                              void* d_out, int out_size, void* d_ws, size_t ws_size,
                              hipStream_t stream) {
    const int*   user_ids    = (const int*)  d_in[0];
    const int*   item_ids    = (const int*)  d_in[1];
    const float* item_know   = (const float*)d_in[2];
    const float* priori      = (const float*)d_in[3];
    const float* condi_p     = (const float*)d_in[4];
    const float* condi_n     = (const float*)d_in[5];
    const float* item_diff_w = (const float*)d_in[6];
    const float* item_disc_w = (const float*)d_in[7];
    const float* Wu          = (const float*)d_in[8];
    const float* bu          = (const float*)d_in[9];
    const float* Wi          = (const float*)d_in[10];
    const float* bi          = (const float*)d_in[11];
    float* out = (float*)d_out;

    char* base = (char*)d_ws;
    u16*   wsp   = (u16*)base;                                    // 256 KiB
    uint2* cbT16 = (uint2*)(base + 0x40000);                      // 127*BATCH*8 B ~16.6 MiB
    const size_t cbBytes = (size_t)127 * BATCH * 8;
    u32* dhiw = (u32*)(base + 0x40000 + cbBytes);                 // 4 MiB
    u32* dlow = (u32*)(base + 0x40000 + cbBytes + 0x400000);      // 4 MiB
    u32* kmw  = (u32*)(base + 0x40000 + cbBytes + 0x800000);      // 4 MiB
    const size_t need = 0x40000 + cbBytes + 0xC00000;             // ~28.9 MiB

    if (ws_size >= need) {
        gather_ncd<<<BATCH / 4, 256, 0, stream>>>(
            user_ids, item_ids, item_know, priori, condi_p, condi_n,
            item_diff_w, Wu, Wi, wsp, cbT16, dhiw, dlow, kmw);
        cg_ncd<<<BATCH / 32, 256, 0, stream>>>(
            item_ids, item_disc_w, bu, bi, wsp, cbT16,
            dhiw, dlow, kmw, out);
    } else {
        conv_w<<<256, 256, 0, stream>>>(Wu, Wi, wsp);
        fused_ncd<<<BATCH / RPB, 256, 0, stream>>>(
            user_ids, item_ids, item_know, priori, condi_p, condi_n,
            item_diff_w, item_disc_w, bu, bi, wsp, out);
    }
}

// Round 23
// 48.548 us; speedup vs baseline: 1.0342x; 1.0342x over previous
//
#include <hip/hip_runtime.h>
#include <hip/hip_fp16.h>

#define BATCH   16384
#define NKNOW   128
#define NEDGE   253
#define RPB     16

typedef __attribute__((ext_vector_type(8))) short  s16x8;   // 8 bf16 MFMA operand
typedef __attribute__((ext_vector_type(4))) float  f32x4;   // MFMA accumulator
typedef __attribute__((ext_vector_type(4))) int    i32x4;

typedef unsigned short u16;
typedef unsigned int   u32;
typedef unsigned long long u64;

__device__ __forceinline__ float sigm(float x) { return 1.0f / (1.0f + __expf(-x)); }

__device__ __forceinline__ u16 f2bf_rn(float x) {
    u32 u = __float_as_uint(x);
    u += 0x7FFFu + ((u >> 16) & 1u);
    return (u16)(u >> 16);
}
__device__ __forceinline__ float bf2f(u16 h) { return __uint_as_float(((u32)h) << 16); }

// centered-f16 pack: store f16(c - 0.5) for c in (0,1); half-ulp <= ~1.2e-4
__device__ __forceinline__ u16 f2hc(float x) {
    __half h = __float2half_rn(x - 0.5f);
    u16 v; __builtin_memcpy(&v, &h, 2); return v;
}
__device__ __forceinline__ float h2fc(u32 u) {      // low 16 bits -> centered value
    u16 v = (u16)u; __half h; __builtin_memcpy(&h, &v, 2);
    return __half2float(h);
}

// R1-proven LDS swizzle: row-major 256B rows, XOR bits 4-6 with row&7
__device__ __forceinline__ int swz(int row, int kbyte) {
    return row * 256 + (kbyte ^ ((row & 7) << 4));
}
__device__ __forceinline__ void store_pair(char* Mh, char* Ml, int r, int k0, float va, float vb) {
    int off = swz(r, k0 * 2);
    u16 ha = f2bf_rn(va); u16 la = f2bf_rn(va - bf2f(ha));
    u16 hb = f2bf_rn(vb); u16 lb = f2bf_rn(vb - bf2f(hb));
    *(u32*)(Mh + off) = (u32)ha | ((u32)hb << 16);
    *(u32*)(Ml + off) = (u32)la | ((u32)lb << 16);
}

// ======================= K1: gather (+ merged conv_w) ======================
// cbT16[slot][row] (slot-major, BATCH stride, uint2 = 4 centered-f16):
//   slot 0      = header (sig cp0, sig cn0, sig priori0, 0)
//   slot 1..126 = step k=slot+1: (cpa,cna,cpb,cnb) sqrt'd sigmoids
__global__ __launch_bounds__(256, 4) void gather_ncd(
    const int*   __restrict__ user_ids,
    const float* __restrict__ priori,
    const float* __restrict__ condi_p,
    const float* __restrict__ condi_n,
    const float* __restrict__ Wu,
    const float* __restrict__ Wi,
    u16*         __restrict__ wsp,
    uint2*       __restrict__ cbT16)
{
    __shared__ float4 stage[4][128];        // [rr][slot], 8 KB

    const int wid = threadIdx.x >> 6, j = threadIdx.x & 63;
    const int r0  = blockIdx.x * 4;
    const int row = r0 + wid;
    const int uid = user_ids[row];
    const float* cp = condi_p + (size_t)uid * NEDGE;
    const float* cn = condi_n + (size_t)uid * NEDGE;

    // issue all independent loads up front
    float a0p = cp[127 + j], a0n = cn[127 + j], b0p = cp[1 + j], b0n = cn[1 + j];
    float a1p = 0.f, a1n = 0.f, b1p = 0.f, b1n = 0.f;
    if (j < 62) { a1p = cp[191 + j]; a1n = cn[191 + j]; b1p = cp[65 + j]; b1n = cn[65 + j]; }
    float c0p = cp[0], c0n = cn[0], pri = priori[(size_t)uid * NKNOW];

    float4 sA;
    sA.x = sqrtf(sigm(a0p)); sA.y = sqrtf(sigm(a0n));
    sA.z = sqrtf(sigm(b0p)); sA.w = sqrtf(sigm(b0n));
    stage[wid][1 + j] = sA;
    if (j < 62) {
        float4 sB;
        sB.x = sqrtf(sigm(a1p)); sB.y = sqrtf(sigm(a1n));
        sB.z = sqrtf(sigm(b1p)); sB.w = sqrtf(sigm(b1n));
        stage[wid][65 + j] = sB;
    }
    if (j == 0) {
        float4 h; h.x = sigm(c0p); h.y = sigm(c0n); h.z = sigm(pri); h.w = 0.5f;
        stage[wid][0] = h;
    }
    __syncthreads();

    // transposed write-out (centered-f16 packed): 127 slots x 4 rows
    for (int idx = threadIdx.x; idx < 4 * 127; idx += 256) {
        const int slot = idx >> 2, rr = idx & 3;
        float4 v = stage[rr][slot];
        uint2 o;
        o.x = (u32)f2hc(v.x) | ((u32)f2hc(v.y) << 16);
        o.y = (u32)f2hc(v.z) | ((u32)f2hc(v.w) << 16);
        cbT16[(size_t)slot * BATCH + r0 + rr] = o;
    }

    // merged conv_w: blocks 0..255 convert Wu/Wi fp32 -> bf16 hi/lo in wsp
    if (blockIdx.x < 256) {
        int i = blockIdx.x * 256 + threadIdx.x;          // 0..65535
        bool isU = i < 32768;
        int  jj  = isU ? i : i - 32768;
        float w  = isU ? Wu[jj] : Wi[jj];
        u16 h = f2bf_rn(w);
        u16 l = f2bf_rn(w - bf2f(h));
        int base = isU ? 0 : 65536;
        wsp[base + jj]         = h;
        wsp[base + 32768 + jj] = l;
    }
}

// ======================= K2: chain + D-prep + gemm (champion, occ 2) =======
// 512 blocks x 256 thr, 32 rows/block; f16 chain coeffs.
// Phase A: wave0 lanes0-31 = 32 serial chains (coalesced cbT16 reads);
//          wave0 lanes32-63 = disc; waves1-2 = know/diff gather.
// Phase B: champion MFMA gemm (mask-AND on A), 2 row-groups of 16.
__global__ __launch_bounds__(256, 2) void cg_ncd(
    const int*   __restrict__ item_ids,
    const float* __restrict__ item_know,
    const float* __restrict__ item_diff_w,
    const float* __restrict__ item_disc_w,
    const float* __restrict__ bu,
    const float* __restrict__ bi,
    const u16*   __restrict__ wsp,
    const uint2* __restrict__ cbT16,
    float*       __restrict__ out)
{
    __shared__ __align__(16) u16 sMh[32 * 128];
    __shared__ __align__(16) u16 sMl[32 * 128];
    __shared__ __align__(16) u16 sDh[32 * 128];
    __shared__ __align__(16) u16 sDl[32 * 128];
    __shared__ __align__(16) u16 sKm[32 * 128];
    __shared__ float sRed[4][32];
    __shared__ float sDisc[32];

    const int tid  = threadIdx.x;
    const int lane = tid & 63;
    const int wid  = tid >> 6;
    const int l15  = lane & 15, lq = lane >> 4;
    const int r0   = blockIdx.x * 32;

    if (wid == 0) {
        if (lane < 32) {
            // ---- 32 serial chains, coalesced cbT16 reads -----------------
            const int r = lane;
            const uint2* base = cbT16 + (r0 + r);
            uint2 hh = base[0];
            float c0p = h2fc(hh.x) + 0.5f;
            float c0n = h2fc(hh.x >> 16) + 0.5f;
            float p0  = h2fc(hh.y) + 0.5f;
            float p1  = fmaf(p0, c0p - c0n, c0n);
            store_pair((char*)sMh, (char*)sMl, r, 0, p0, p1);

            float pm2 = p0, pm1 = p1, pev = 0.f;
            uint2 A[14], Bv[14];
#define LOADB(buf, bi_)                                               \
    _Pragma("unroll")                                                 \
    for (int t = 0; t < 14; ++t)                                      \
        buf[t] = base[(size_t)(1 + 14 * (bi_) + t) * BATCH];
#define STEPS(buf, bi_)                                               \
    _Pragma("unroll")                                                 \
    for (int t = 0; t < 14; ++t) {                                    \
        const int k = 2 + 14 * (bi_) + t;                             \
        uint2 sv = buf[t];                                            \
        float ax = h2fc(sv.x), ay = h2fc(sv.x >> 16);                 \
        float bx = h2fc(sv.y), by = h2fc(sv.y >> 16);                 \
        float ta = fmaf(pm2, ax - ay, ay + 0.5f);                     \
        float tb = fmaf(pm1, bx - by, by + 0.5f);                     \
        float pk = ta * tb;                                           \
        if (k & 1) store_pair((char*)sMh, (char*)sMl, r, k - 1, pev, pk); \
        else       pev = pk;                                          \
        pm2 = pm1; pm1 = pk;                                          \
    }
            LOADB(A, 0);
            LOADB(Bv, 1); STEPS(A, 0);
            LOADB(A, 2);  STEPS(Bv, 1);
            LOADB(Bv, 3); STEPS(A, 2);
            LOADB(A, 4);  STEPS(Bv, 3);
            LOADB(Bv, 5); STEPS(A, 4);
            LOADB(A, 6);  STEPS(Bv, 5);
            LOADB(Bv, 7); STEPS(A, 6);
            LOADB(A, 8);  STEPS(Bv, 7);
            STEPS(A, 8);
#undef LOADB
#undef STEPS
        } else {
            sDisc[lane - 32] = sigm(item_disc_w[item_ids[r0 + lane - 32]]);
        }
    } else if (wid <= 2) {
        const int rbase = (wid - 1) * 16;
        for (int rr = 0; rr < 16; ++rr) {
            const int r = rbase + rr, row = r0 + r;
            const int iid = item_ids[row];
            const float* kw = item_know   + (size_t)row * NKNOW;
            const float* dw = item_diff_w + (size_t)iid * NKNOW;
            #pragma unroll
            for (int half = 0; half < 2; ++half) {
                const int e = half * 64 + lane;
                float kv = kw[e];
                float dv = sigm(dw[e]) * kv;              // know in {0,1} -> exact
                u16 dh = f2bf_rn(dv);
                u16 dl = f2bf_rn(dv - bf2f(dh));
                const int off = swz(r, 2 * e);
                *(u16*)((char*)sDh + off) = dh;
                *(u16*)((char*)sDl + off) = dl;
                *(u16*)((char*)sKm + off) = (kv > 0.5f) ? (u16)0xFFFFu : (u16)0;
            }
        }
    }
    __syncthreads();

    // ---------------- Phase B: MFMA gemm (champion verbatim) --------------
    const u16* WuH = wsp;
    const u16* WuL = wsp + 32768;
    const u16* WiH = wsp + 65536;
    const u16* WiL = wsp + 98304;

    float rowsum[2][4] = {{0.f,0.f,0.f,0.f},{0.f,0.f,0.f,0.f}};

    #pragma unroll 1
    for (int t = 0; t < 4; ++t) {
        const int hcol = wid * 64 + t * 16 + l15;
        s16x8 uh[4], ul[4], ih[4], il[4];
        #pragma unroll
        for (int kc = 0; kc < 4; ++kc) {
            const int ke = kc * 32 + lq * 8;
            uh[kc] = *(const s16x8*)(WuH + hcol * NKNOW + ke);
            ul[kc] = *(const s16x8*)(WuL + hcol * NKNOW + ke);
            ih[kc] = *(const s16x8*)(WiH + hcol * NKNOW + ke);
            il[kc] = *(const s16x8*)(WiL + hcol * NKNOW + ke);
        }
        const float bub = bu[hcol], bib = bi[hcol];

        #pragma unroll
        for (int rg = 0; rg < 2; ++rg) {
            const int lr = rg * 16 + l15;                 // LDS row 0..31
            f32x4 accU = {0.f, 0.f, 0.f, 0.f};
            f32x4 accV = {0.f, 0.f, 0.f, 0.f};
            #pragma unroll
            for (int kc = 0; kc < 4; ++kc) {
                const int offA = swz(lr, kc * 64 + lq * 16);
                i32x4 km = *(const i32x4*)((const char*)sKm + offA);
                i32x4 mh = *(const i32x4*)((const char*)sMh + offA) & km;
                i32x4 ml = *(const i32x4*)((const char*)sMl + offA) & km;
                s16x8 ah = *(s16x8*)&mh;
                s16x8 al = *(s16x8*)&ml;
                s16x8 dh = *(const s16x8*)((const char*)sDh + offA);
                s16x8 dl = *(const s16x8*)((const char*)sDl + offA);
                accU = __builtin_amdgcn_mfma_f32_16x16x32_bf16(ah, uh[kc], accU, 0, 0, 0);
                accU = __builtin_amdgcn_mfma_f32_16x16x32_bf16(ah, ul[kc], accU, 0, 0, 0);
                accU = __builtin_amdgcn_mfma_f32_16x16x32_bf16(al, uh[kc], accU, 0, 0, 0);
                accV = __builtin_amdgcn_mfma_f32_16x16x32_bf16(dh, ih[kc], accV, 0, 0, 0);
                accV = __builtin_amdgcn_mfma_f32_16x16x32_bf16(dh, il[kc], accV, 0, 0, 0);
                accV = __builtin_amdgcn_mfma_f32_16x16x32_bf16(dl, ih[kc], accV, 0, 0, 0);
            }
            #pragma unroll
            for (int j = 0; j < 4; ++j) {                 // C/D: col=l15, row=lq*4+j
                float x = accU[j] + bub;
                float u = 1.0f - 2.0f / (1.0f + __expf(2.0f * x));   // tanh
                float v = sigm(accV[j] + bib);
                rowsum[rg][j] += u * v;
            }
        }
    }

    #pragma unroll
    for (int rg = 0; rg < 2; ++rg)
        #pragma unroll
        for (int j = 0; j < 4; ++j) {
            float v = rowsum[rg][j];
            v += __shfl_xor(v, 1);
            v += __shfl_xor(v, 2);
            v += __shfl_xor(v, 4);
            v += __shfl_xor(v, 8);
            if (l15 == 0) sRed[wid][rg * 16 + lq * 4 + j] = v;
        }
    __syncthreads();

    if (tid < 32) {
        float s = sRed[0][tid] + sRed[1][tid] + sRed[2][tid] + sRed[3][tid];
        out[r0 + tid] = sigm(s - sDisc[tid]);
    }
}

// ======================= Fallback: R1 fused kernel (proven) ================
__global__ void conv_w(const float* __restrict__ Wu, const float* __restrict__ Wi,
                       u16* __restrict__ wsp) {
    int i = blockIdx.x * 256 + threadIdx.x;
    bool isU = i < 32768;
    int  j   = isU ? i : i - 32768;
    float w  = isU ? Wu[j] : Wi[j];
    u16 h = f2bf_rn(w);
    u16 l = f2bf_rn(w - bf2f(h));
    int base = isU ? 0 : 65536;
    wsp[base + j]         = h;
    wsp[base + 32768 + j] = l;
}

__global__ __launch_bounds__(256, 3) void fused_ncd(
    const int*   __restrict__ user_ids,
    const int*   __restrict__ item_ids,
    const float* __restrict__ item_know,
    const float* __restrict__ priori,
    const float* __restrict__ condi_p,
    const float* __restrict__ condi_n,
    const float* __restrict__ item_diff_w,
    const float* __restrict__ item_disc_w,
    const float* __restrict__ bu,
    const float* __restrict__ bi,
    const u16* __restrict__ wsp,
    float*       __restrict__ out)
{
    __shared__ float sPair[RPB][508];
    __shared__ __align__(16) u16 sMhi[RPB * 128];
    __shared__ __align__(16) u16 sMlo[RPB * 128];
    __shared__ __align__(16) u16 sDhi[RPB * 128];
    __shared__ __align__(16) u16 sDlo[RPB * 128];
    __shared__ __align__(16) u16 sKmF[RPB * 128];
    __shared__ float sRed[4][RPB];
    __shared__ float sDisc[RPB];

    const int tid  = threadIdx.x;
    const int lane = tid & 63;
    const int wid  = tid >> 6;
    const int r0   = blockIdx.x * RPB;

    for (int rr = 0; rr < 4; ++rr) {
        const int r   = wid * 4 + rr;
        const int row = r0 + r;
        const int uid = user_ids[row];
        const int iid = item_ids[row];
        const float* cp = condi_p + (size_t)uid * NEDGE;
        const float* cn = condi_n + (size_t)uid * NEDGE;
        for (int e = lane; e < NEDGE; e += 64) {
            float p = sigm(cp[e]);
            float n = sigm(cn[e]);
            if (e >= 1) { p = sqrtf(p); n = sqrtf(n); }
            *(float2*)&sPair[r][2 * e] = make_float2(p, n);
        }
        const float* dw = item_diff_w + (size_t)iid * NKNOW;
        const float* kw = item_know   + (size_t)row * NKNOW;
        for (int e = lane; e < NKNOW; e += 64) {
            float kv = kw[e];
            float dv = sigm(dw[e]) * kv;
            u16 dh = f2bf_rn(dv);
            u16 dl = f2bf_rn(dv - bf2f(dh));
            int off = swz(r, 2 * e);
            *(u16*)((char*)sDhi + off) = dh;
            *(u16*)((char*)sDlo + off) = dl;
            *(u16*)((char*)sKmF + off) = (kv > 0.5f) ? (u16)0xFFFFu : (u16)0;
        }
    }
    __syncthreads();

    if (tid < RPB) {
        const int r   = tid;
        const int row = r0 + r;
        const int uid = user_ids[row];
        const int iid = item_ids[row];
        const float* P = &sPair[r][0];
        float p0 = sigm(priori[(size_t)uid * NKNOW]);
        float2 c0 = *(const float2*)&P[0];
        float p1 = c0.x * p0 + c0.y * (1.0f - p0);
        store_pair((char*)sMhi, (char*)sMlo, r, 0, p0, p1);
        float pm2 = p0, pm1 = p1, pev = 0.0f;
        for (int k = 2; k < NKNOW; ++k) {
            float2 a = *(const float2*)&P[2 * (125 + k)];
            float2 b = *(const float2*)&P[2 * (k - 1)];
            float ta = fmaf(pm2, a.x - a.y, a.y);
            float tb = fmaf(pm1, b.x - b.y, b.y);
            float pk = ta * tb;
            if (k & 1) store_pair((char*)sMhi, (char*)sMlo, r, k - 1, pev, pk);
            else       pev = pk;
            pm2 = pm1; pm1 = pk;
        }
        sDisc[r] = sigm(item_disc_w[iid]);
    }
    __syncthreads();

    const int l15 = lane & 15, lq = lane >> 4;
    const u16* WuH = wsp;
    const u16* WuL = wsp + 32768;
    const u16* WiH = wsp + 65536;
    const u16* WiL = wsp + 98304;

    float rowsum[4] = {0.f, 0.f, 0.f, 0.f};

    for (int t = 0; t < 4; ++t) {
        const int hcol = wid * 64 + t * 16 + l15;
        f32x4 accU = {0.f, 0.f, 0.f, 0.f};
        f32x4 accV = {0.f, 0.f, 0.f, 0.f};
        const u16* wuh = WuH + hcol * NKNOW;
        const u16* wul = WuL + hcol * NKNOW;
        const u16* wih = WiH + hcol * NKNOW;
        const u16* wil = WiL + hcol * NKNOW;
        #pragma unroll
        for (int kc = 0; kc < 4; ++kc) {
            const int offA = swz(l15, kc * 64 + lq * 16);
            const int ke   = kc * 32 + lq * 8;
            i32x4 km = *(const i32x4*)((const char*)sKmF + offA);
            i32x4 mh = *(const i32x4*)((const char*)sMhi + offA) & km;
            i32x4 ml = *(const i32x4*)((const char*)sMlo + offA) & km;
            s16x8 ah = *(s16x8*)&mh;
            s16x8 al = *(s16x8*)&ml;
            s16x8 bh = *(const s16x8*)((const char*)sDhi + offA);
            s16x8 bl = *(const s16x8*)((const char*)sDlo + offA);
            s16x8 uh = *(const s16x8*)(wuh + ke);
            s16x8 ul = *(const s16x8*)(wul + ke);
            s16x8 ih = *(const s16x8*)(wih + ke);
            s16x8 il = *(const s16x8*)(wil + ke);
            accU = __builtin_amdgcn_mfma_f32_16x16x32_bf16(ah, uh, accU, 0, 0, 0);
            accU = __builtin_amdgcn_mfma_f32_16x16x32_bf16(ah, ul, accU, 0, 0, 0);
            accU = __builtin_amdgcn_mfma_f32_16x16x32_bf16(al, uh, accU, 0, 0, 0);
            accV = __builtin_amdgcn_mfma_f32_16x16x32_bf16(bh, ih, accV, 0, 0, 0);
            accV = __builtin_amdgcn_mfma_f32_16x16x32_bf16(bh, il, accV, 0, 0, 0);
            accV = __builtin_amdgcn_mfma_f32_16x16x32_bf16(bl, ih, accV, 0, 0, 0);
        }
        const float bub = bu[hcol], bib = bi[hcol];
        #pragma unroll
        for (int j = 0; j < 4; ++j) {
            float x = accU[j] + bub;
            float u = 1.0f - 2.0f / (1.0f + __expf(2.0f * x));
            float v = sigm(accV[j] + bib);
            rowsum[j] += u * v;
        }
    }

    #pragma unroll
    for (int j = 0; j < 4; ++j) {
        float v = rowsum[j];
        v += __shfl_xor(v, 1);
        v += __shfl_xor(v, 2);
        v += __shfl_xor(v, 4);
        v += __shfl_xor(v, 8);
        if (l15 == 0) sRed[wid][lq * 4 + j] = v;
    }
    __syncthreads();

    if (tid < RPB) {
        float logit = sRed[0][tid] + sRed[1][tid] + sRed[2][tid] + sRed[3][tid] - sDisc[tid];
        out[r0 + tid] = sigm(logit);
    }
}

extern "C" void kernel_launch(void* const* d_in, const int* in_sizes, int n_in,
                              void* d_out, int out_size, void* d_ws, size_t ws_size,
                              hipStream_t stream) {
    const int*   user_ids    = (const int*)  d_in[0];
    const int*   item_ids    = (const int*)  d_in[1];
    const float* item_know   = (const float*)d_in[2];
    const float* priori      = (const float*)d_in[3];
    const float* condi_p     = (const float*)d_in[4];
    const float* condi_n     = (const float*)d_in[5];
    const float* item_diff_w = (const float*)d_in[6];
    const float* item_disc_w = (const float*)d_in[7];
    const float* Wu          = (const float*)d_in[8];
    const float* bu          = (const float*)d_in[9];
    const float* Wi          = (const float*)d_in[10];
    const float* bi          = (const float*)d_in[11];
    float* out = (float*)d_out;

    char* base = (char*)d_ws;
    u16*   wsp   = (u16*)base;                                    // 256 KiB
    uint2* cbT16 = (uint2*)(base + 0x40000);                      // 127*BATCH*8 B
    const size_t need = 0x40000 + (size_t)127 * BATCH * 8;        // ~16.9 MiB

    if (ws_size >= need) {
        gather_ncd<<<BATCH / 4, 256, 0, stream>>>(
            user_ids, priori, condi_p, condi_n, Wu, Wi, wsp, cbT16);
        cg_ncd<<<BATCH / 32, 256, 0, stream>>>(
            item_ids, item_know, item_diff_w, item_disc_w, bu, bi,
            wsp, cbT16, out);
    } else {
        conv_w<<<256, 256, 0, stream>>>(Wu, Wi, wsp);
        fused_ncd<<<BATCH / RPB, 256, 0, stream>>>(
            user_ids, item_ids, item_know, priori, condi_p, condi_n,
            item_diff_w, item_disc_w, bu, bi, wsp, out);
    }
}